// Round 1
// baseline (1180.037 us; speedup 1.0000x reference)
//
#include <hip/hip_runtime.h>
#include <float.h>
#include <math.h>

#define NV 50257
#define D 128
#define B 2048
#define C 10
#define NCHUNK 8
#define CW ((NV + NCHUNK - 1) / NCHUNK)   // 6283
#define TB 32
#define TN 64
#define WPAD (D + 4)                       // 132 floats: 16B-aligned rows, even bank spread

__device__ __forceinline__ float softplus_f(float x) {
    return fmaxf(x, 0.f) + log1pf(expf(-fabsf(x)));
}

// ---------------- Kernel A: inference net, z = mu + eps*sigma, KL per row ----------------
__global__ __launch_bounds__(128) void k_infer(
    const int* __restrict__ x_batch, const int* __restrict__ ctxw,
    const float* __restrict__ eps, const float* __restrict__ inf_emb,
    const float* __restrict__ W_aff, const float* __restrict__ b_aff,
    const float* __restrict__ W_mu, const float* __restrict__ b_mu,
    const float* __restrict__ W_sig, const float* __restrict__ b_sig,
    const float* __restrict__ gen_sig_emb,
    float* __restrict__ z_out, float* __restrict__ kl_out)
{
    const int b = blockIdx.x;
    const int d = threadIdx.x;      // 0..127

    __shared__ float center_s[D];
    __shared__ float ctx_s[C][D];
    __shared__ float hsum_s[D];
    __shared__ float red_s[2];

    const int xb = x_batch[b];
    center_s[d] = inf_emb[xb * D + d];
    #pragma unroll
    for (int c = 0; c < C; ++c) {
        const int ci = ctxw[b * C + c];
        ctx_s[c][d] = inf_emb[ci * D + d];
    }
    __syncthreads();

    // h[b,c,d] = relu(center . W_aff[d,0:D] + ctx_c . W_aff[d,D:2D] + b_aff[d])
    const float* wrow = W_aff + d * (2 * D);
    float u = 0.f;
    for (int e = 0; e < D; ++e) u = fmaf(center_s[e], wrow[e], u);
    float v[C];
    #pragma unroll
    for (int c = 0; c < C; ++c) v[c] = 0.f;
    for (int e = 0; e < D; ++e) {
        const float w2 = wrow[D + e];
        #pragma unroll
        for (int c = 0; c < C; ++c) v[c] = fmaf(ctx_s[c][e], w2, v[c]);
    }
    const float ba = b_aff[d];
    float hs = 0.f;
    #pragma unroll
    for (int c = 0; c < C; ++c) hs += fmaxf(u + v[c] + ba, 0.f);
    hsum_s[d] = hs;
    __syncthreads();

    // mu, sigma
    const float* wm = W_mu + d * D;
    const float* wsg = W_sig + d * D;
    float mu = 0.f, sg = 0.f;
    for (int e = 0; e < D; ++e) {
        const float h = hsum_s[e];
        mu = fmaf(h, wm[e], mu);
        sg = fmaf(h, wsg[e], sg);
    }
    mu += b_mu[d];
    sg += b_sig[d];
    const float isig = softplus_f(sg);
    const float zz = fmaf(eps[b * D + d], isig, mu);
    z_out[b * D + d] = zz;

    // KL element
    const float gs = softplus_f(gen_sig_emb[xb * D + d]);
    const float diff = mu - gs;
    float kld = logf(gs / isig) + (isig * isig + diff * diff) / (2.f * gs * gs) - 0.5f;

    // block reduce (2 waves)
    #pragma unroll
    for (int off = 32; off > 0; off >>= 1) kld += __shfl_down(kld, off, 64);
    const int lane = d & 63, wv = d >> 6;
    if (lane == 0) red_s[wv] = kld;
    __syncthreads();
    if (d == 0) kl_out[b] = red_s[0] + red_s[1];
}

// ---------------- Kernel B: streaming logsumexp over vocab (flash-style) ----------------
// grid (B/TB, NCHUNK), block 256. Each wave owns 8 rows; thread = 1 column x 8 rows.
__global__ __launch_bounds__(256) void k_lse(
    const float* __restrict__ z, const float* __restrict__ W_gen,
    const float* __restrict__ b_gen,
    float* __restrict__ part_m, float* __restrict__ part_s)
{
    const int rg = blockIdx.x;       // row group 0..63
    const int chunk = blockIdx.y;    // 0..NCHUNK-1
    const int t = threadIdx.x;
    const int rowbase = rg * TB;
    const int start = chunk * CW;
    const int end = min(start + CW, NV);

    __shared__ float z_s[TB * D];        // 16 KB
    __shared__ float w_s[TN * WPAD];     // ~33 KB
    __shared__ float bg_s[TN];

    // load z tile (coalesced float4)
    {
        const float4* zsrc = (const float4*)(z + rowbase * D);
        float4* zdst = (float4*)z_s;
        #pragma unroll
        for (int k = 0; k < (TB * D / 4) / 256; ++k)
            zdst[t + k * 256] = zsrc[t + k * 256];
    }

    const int col = t & 63;
    const int rg4 = t >> 6;          // wave id = row subgroup
    const int r0 = rg4 * 8;
    float acc_m[8], acc_s[8];
    #pragma unroll
    for (int j = 0; j < 8; ++j) { acc_m[j] = -FLT_MAX; acc_s[j] = 0.f; }

    for (int n0 = start; n0 < end; n0 += TN) {
        __syncthreads();   // w_s safe to overwrite (also covers first-iter z_s)
        // stage W tile: 64 rows x 128 floats = 2048 float4, 8 per thread, coalesced
        #pragma unroll
        for (int k = 0; k < 8; ++k) {
            const int idx = t + k * 256;
            const int row = idx >> 5;
            const int c4 = idx & 31;
            const int n = n0 + row;
            float4 g = make_float4(0.f, 0.f, 0.f, 0.f);
            if (n < end) g = ((const float4*)W_gen)[n * (D / 4) + c4];
            *(float4*)&w_s[row * WPAD + c4 * 4] = g;
        }
        if (t < TN) bg_s[t] = (n0 + t < end) ? b_gen[n0 + t] : 0.f;
        __syncthreads();

        const bool valid = (n0 + col) < end;
        float acc[8];
        #pragma unroll
        for (int j = 0; j < 8; ++j) acc[j] = 0.f;
        const float* wbase = &w_s[col * WPAD];
        const float* zbase = &z_s[r0 * D];
        #pragma unroll 4
        for (int d4 = 0; d4 < D / 4; ++d4) {
            const float4 wv = *(const float4*)(wbase + d4 * 4);
            #pragma unroll
            for (int j = 0; j < 8; ++j) {
                const float4 zv = *(const float4*)(zbase + j * D + d4 * 4);
                acc[j] = fmaf(wv.x, zv.x, acc[j]);
                acc[j] = fmaf(wv.y, zv.y, acc[j]);
                acc[j] = fmaf(wv.z, zv.z, acc[j]);
                acc[j] = fmaf(wv.w, zv.w, acc[j]);
            }
        }
        if (valid) {
            const float bg = bg_s[col];
            #pragma unroll
            for (int j = 0; j < 8; ++j) {
                const float logit = acc[j] + bg;
                const float mo = acc_m[j];
                const float mn = fmaxf(mo, logit);
                acc_s[j] = acc_s[j] * __expf(mo - mn) + __expf(logit - mn);
                acc_m[j] = mn;
            }
        }
    }

    // butterfly merge across the wave (all lanes of a wave share the same 8 rows)
    #pragma unroll
    for (int off = 1; off < 64; off <<= 1) {
        #pragma unroll
        for (int j = 0; j < 8; ++j) {
            const float om = __shfl_xor(acc_m[j], off, 64);
            const float os = __shfl_xor(acc_s[j], off, 64);
            const float mn = fmaxf(acc_m[j], om);
            acc_s[j] = acc_s[j] * __expf(acc_m[j] - mn) + os * __expf(om - mn);
            acc_m[j] = mn;
        }
    }
    if (col == 0) {
        #pragma unroll
        for (int j = 0; j < 8; ++j) {
            const int row = rowbase + r0 + j;
            part_m[row * NCHUNK + chunk] = acc_m[j];
            part_s[row * NCHUNK + chunk] = acc_s[j];
        }
    }
}

// ---------------- Kernel C: per-row finalize (combine chunks, context logits, loss_b) ----------------
__global__ __launch_bounds__(64) void k_final_row(
    const float* __restrict__ z, const float* __restrict__ W_gen,
    const float* __restrict__ b_gen, const int* __restrict__ ctxw,
    const float* __restrict__ part_m, const float* __restrict__ part_s,
    const float* __restrict__ kl, float* __restrict__ loss_b)
{
    const int b = blockIdx.x;
    const int lane = threadIdx.x;    // 0..63

    float M = -FLT_MAX;
    #pragma unroll
    for (int i = 0; i < NCHUNK; ++i) M = fmaxf(M, part_m[b * NCHUNK + i]);
    float S = 0.f;
    #pragma unroll
    for (int i = 0; i < NCHUNK; ++i)
        S += part_s[b * NCHUNK + i] * __expf(part_m[b * NCHUNK + i] - M);
    const float lse = M + logf(S);

    const float z0 = z[b * D + lane * 2];
    const float z1 = z[b * D + lane * 2 + 1];
    float recon = 0.f;
    for (int c = 0; c < C; ++c) {
        const int idx = ctxw[b * C + c];
        float p = z0 * W_gen[idx * D + lane * 2] + z1 * W_gen[idx * D + lane * 2 + 1];
        #pragma unroll
        for (int off = 32; off > 0; off >>= 1) p += __shfl_xor(p, off, 64);
        recon += p + b_gen[idx] - lse;
    }
    if (lane == 0) loss_b[b] = kl[b] - recon;
}

// ---------------- Kernel D: deterministic mean ----------------
__global__ __launch_bounds__(256) void k_reduce(
    const float* __restrict__ loss_b, float* __restrict__ out)
{
    const int t = threadIdx.x;
    float s = 0.f;
    for (int i = t; i < B; i += 256) s += loss_b[i];
    __shared__ float red[4];
    #pragma unroll
    for (int off = 32; off > 0; off >>= 1) s += __shfl_down(s, off, 64);
    if ((t & 63) == 0) red[t >> 6] = s;
    __syncthreads();
    if (t == 0) out[0] = (red[0] + red[1] + red[2] + red[3]) * (1.f / B);
}

extern "C" void kernel_launch(void* const* d_in, const int* in_sizes, int n_in,
                              void* d_out, int out_size, void* d_ws, size_t ws_size,
                              hipStream_t stream) {
    const int* x_batch = (const int*)d_in[0];
    const int* ctxw    = (const int*)d_in[1];
    const float* eps   = (const float*)d_in[2];
    const float* inf_emb = (const float*)d_in[3];
    const float* W_aff = (const float*)d_in[4];
    const float* b_aff = (const float*)d_in[5];
    const float* W_mu  = (const float*)d_in[6];
    const float* b_mu  = (const float*)d_in[7];
    const float* W_sig = (const float*)d_in[8];
    const float* b_sig = (const float*)d_in[9];
    const float* gen_sig = (const float*)d_in[10];
    const float* W_gen = (const float*)d_in[11];
    const float* b_gen = (const float*)d_in[12];
    float* out = (float*)d_out;

    float* ws = (float*)d_ws;
    float* z      = ws;                      // B*D
    float* kl     = z + B * D;               // B
    float* part_m = kl + B;                  // B*NCHUNK
    float* part_s = part_m + B * NCHUNK;     // B*NCHUNK
    float* loss_b = part_s + B * NCHUNK;     // B

    hipLaunchKernelGGL(k_infer, dim3(B), dim3(128), 0, stream,
                       x_batch, ctxw, eps, inf_emb, W_aff, b_aff, W_mu, b_mu,
                       W_sig, b_sig, gen_sig, z, kl);
    hipLaunchKernelGGL(k_lse, dim3(B / TB, NCHUNK), dim3(256), 0, stream,
                       z, W_gen, b_gen, part_m, part_s);
    hipLaunchKernelGGL(k_final_row, dim3(B), dim3(64), 0, stream,
                       z, W_gen, b_gen, ctxw, part_m, part_s, kl, loss_b);
    hipLaunchKernelGGL(k_reduce, dim3(1), dim3(256), 0, stream, loss_b, out);
}

// Round 2
// 276.280 us; speedup vs baseline: 4.2712x; 4.2712x over previous
//
#include <hip/hip_runtime.h>
#include <float.h>
#include <math.h>

#define NV 50257
#define D 128
#define B 2048
#define C 10

// ---- MFMA LSE kernel geometry ----
#define NVPAD 50272                 // 3142 * 16
#define NTILES (NVPAD / 16)         // 3142 col-tiles of 16
#define NSTREAM 128                 // 32 chunks * 4 waves = independent vocab streams
#define MROWS 64                    // batch rows per block (4 row-tiles of 16)

typedef __attribute__((ext_vector_type(8))) short short8;
typedef __attribute__((ext_vector_type(4))) float float4v;

__device__ __forceinline__ float softplus_f(float x) {
    return fmaxf(x, 0.f) + log1pf(expf(-fabsf(x)));
}

__device__ __forceinline__ short f2bf(float f) {
    unsigned u = __float_as_uint(f);
    unsigned r = (u + 0x7FFFu + ((u >> 16) & 1u)) >> 16;   // RNE
    return (short)r;
}

// ---------------- Kernel W: fp32 -> bf16 convert of W_gen (pad rows zeroed) ----------------
__global__ __launch_bounds__(256) void k_convert_w(
    const float* __restrict__ w, short* __restrict__ out)
{
    const int i4 = blockIdx.x * 256 + threadIdx.x;      // float4 index
    if (i4 >= NVPAD * D / 4) return;
    const int e0 = i4 * 4;
    short4 o;
    if (e0 < NV * D) {
        const float4 g = ((const float4*)w)[i4];
        o.x = f2bf(g.x); o.y = f2bf(g.y); o.z = f2bf(g.z); o.w = f2bf(g.w);
    } else {
        o.x = o.y = o.z = o.w = 0;
    }
    ((short4*)out)[i4] = o;
}

// ---------------- Kernel A: inference net, z = mu + eps*sigma, KL per row ----------------
__global__ __launch_bounds__(128) void k_infer(
    const int* __restrict__ x_batch, const int* __restrict__ ctxw,
    const float* __restrict__ eps, const float* __restrict__ inf_emb,
    const float* __restrict__ W_aff, const float* __restrict__ b_aff,
    const float* __restrict__ W_mu, const float* __restrict__ b_mu,
    const float* __restrict__ W_sig, const float* __restrict__ b_sig,
    const float* __restrict__ gen_sig_emb,
    float* __restrict__ z_out, short* __restrict__ zb_out,
    float* __restrict__ kl_out)
{
    const int b = blockIdx.x;
    const int d = threadIdx.x;      // 0..127

    __shared__ float center_s[D];
    __shared__ float ctx_s[C][D];
    __shared__ float hsum_s[D];
    __shared__ float red_s[2];

    const int xb = x_batch[b];
    center_s[d] = inf_emb[xb * D + d];
    #pragma unroll
    for (int c = 0; c < C; ++c) {
        const int ci = ctxw[b * C + c];
        ctx_s[c][d] = inf_emb[ci * D + d];
    }
    __syncthreads();

    const float* wrow = W_aff + d * (2 * D);
    float u = 0.f;
    for (int e = 0; e < D; ++e) u = fmaf(center_s[e], wrow[e], u);
    float v[C];
    #pragma unroll
    for (int c = 0; c < C; ++c) v[c] = 0.f;
    for (int e = 0; e < D; ++e) {
        const float w2 = wrow[D + e];
        #pragma unroll
        for (int c = 0; c < C; ++c) v[c] = fmaf(ctx_s[c][e], w2, v[c]);
    }
    const float ba = b_aff[d];
    float hs = 0.f;
    #pragma unroll
    for (int c = 0; c < C; ++c) hs += fmaxf(u + v[c] + ba, 0.f);
    hsum_s[d] = hs;
    __syncthreads();

    const float* wm = W_mu + d * D;
    const float* wsg = W_sig + d * D;
    float mu = 0.f, sg = 0.f;
    for (int e = 0; e < D; ++e) {
        const float h = hsum_s[e];
        mu = fmaf(h, wm[e], mu);
        sg = fmaf(h, wsg[e], sg);
    }
    mu += b_mu[d];
    sg += b_sig[d];
    const float isig = softplus_f(sg);
    const float zz = fmaf(eps[b * D + d], isig, mu);
    z_out[b * D + d] = zz;
    zb_out[b * D + d] = f2bf(zz);

    const float gs = softplus_f(gen_sig_emb[xb * D + d]);
    const float diff = mu - gs;
    float kld = logf(gs / isig) + (isig * isig + diff * diff) / (2.f * gs * gs) - 0.5f;

    #pragma unroll
    for (int off = 32; off > 0; off >>= 1) kld += __shfl_down(kld, off, 64);
    const int lane = d & 63, wv = d >> 6;
    if (lane == 0) red_s[wv] = kld;
    __syncthreads();
    if (d == 0) kl_out[b] = red_s[0] + red_s[1];
}

// ---------------- Kernel B: MFMA sum-exp over vocab (fixed shift 0, no LDS, no barriers) ----
// grid (B/MROWS=32, NSTREAM/4=32), block 256 = 4 waves. Each wave: 64 batch rows x
// a strided stream of 16-col vocab tiles. C layout: col=lane&15, row=quad*4+reg.
__global__ __launch_bounds__(256) void k_lse_mfma(
    const short* __restrict__ zb, const short* __restrict__ wb,
    const float* __restrict__ b_gen, float* __restrict__ part_s)
{
    const int rowbase = blockIdx.x * MROWS;
    const int t = threadIdx.x;
    const int wv = t >> 6;
    const int lane = t & 63;
    const int col16 = lane & 15;
    const int quad = lane >> 4;
    const int sid = blockIdx.y * 4 + wv;      // 0..127

    // A fragments: 4 row-tiles x 4 k-steps, each 8 contiguous bf16 (16 B)
    short8 afrag[4][4];
    #pragma unroll
    for (int rt = 0; rt < 4; ++rt)
        #pragma unroll
        for (int ks = 0; ks < 4; ++ks)
            afrag[rt][ks] = *(const short8*)(zb + (rowbase + rt * 16 + col16) * D
                                                + ks * 32 + quad * 8);

    float sums[4][4];
    #pragma unroll
    for (int rt = 0; rt < 4; ++rt)
        #pragma unroll
        for (int r = 0; r < 4; ++r) sums[rt][r] = 0.f;

    for (int tile = sid; tile < NTILES; tile += NSTREAM) {
        const int n0 = tile * 16;
        const int col = n0 + col16;
        const short* wp = wb + (size_t)col * D + quad * 8;
        short8 bfrag[4];
        #pragma unroll
        for (int ks = 0; ks < 4; ++ks)
            bfrag[ks] = *(const short8*)(wp + ks * 32);
        // pad cols: bg = -inf so exp -> 0, no per-element masking needed
        const float bgl = b_gen[col < NV ? col : NV - 1];
        const float bg = (col < NV) ? bgl : -INFINITY;

        #pragma unroll
        for (int rt = 0; rt < 4; ++rt) {
            float4v c = {0.f, 0.f, 0.f, 0.f};
            #pragma unroll
            for (int ks = 0; ks < 4; ++ks)
                c = __builtin_amdgcn_mfma_f32_16x16x32_bf16(afrag[rt][ks], bfrag[ks], c, 0, 0, 0);
            #pragma unroll
            for (int r = 0; r < 4; ++r)
                sums[rt][r] += __expf(c[r] + bg);
        }
    }

    // reduce across the 16 column-lanes (same row lives in lanes differing in low 4 bits)
    #pragma unroll
    for (int off = 1; off < 16; off <<= 1)
        #pragma unroll
        for (int rt = 0; rt < 4; ++rt)
            #pragma unroll
            for (int r = 0; r < 4; ++r)
                sums[rt][r] += __shfl_xor(sums[rt][r], off, 64);

    if (col16 == 0) {
        #pragma unroll
        for (int rt = 0; rt < 4; ++rt)
            #pragma unroll
            for (int r = 0; r < 4; ++r) {
                const int row = rowbase + rt * 16 + quad * 4 + r;
                part_s[row * NSTREAM + sid] = sums[rt][r];
            }
    }
}

// ---------------- Kernel C: per-row finalize ----------------
__global__ __launch_bounds__(64) void k_final_row(
    const float* __restrict__ z, const float* __restrict__ W_gen,
    const float* __restrict__ b_gen, const int* __restrict__ ctxw,
    const float* __restrict__ part_s, const float* __restrict__ kl,
    float* __restrict__ loss_b)
{
    const int b = blockIdx.x;
    const int lane = threadIdx.x;    // 0..63

    float s = part_s[b * NSTREAM + lane] + part_s[b * NSTREAM + 64 + lane];
    #pragma unroll
    for (int off = 32; off > 0; off >>= 1) s += __shfl_xor(s, off, 64);
    const float lse = logf(s);       // fixed shift 0: logits are O(1)

    const float z0 = z[b * D + lane * 2];
    const float z1 = z[b * D + lane * 2 + 1];
    float recon = 0.f;
    for (int c = 0; c < C; ++c) {
        const int idx = ctxw[b * C + c];
        float p = z0 * W_gen[idx * D + lane * 2] + z1 * W_gen[idx * D + lane * 2 + 1];
        #pragma unroll
        for (int off = 32; off > 0; off >>= 1) p += __shfl_xor(p, off, 64);
        recon += p + b_gen[idx] - lse;
    }
    if (lane == 0) loss_b[b] = kl[b] - recon;
}

// ---------------- Kernel D: deterministic mean ----------------
__global__ __launch_bounds__(256) void k_reduce(
    const float* __restrict__ loss_b, float* __restrict__ out)
{
    const int t = threadIdx.x;
    float s = 0.f;
    for (int i = t; i < B; i += 256) s += loss_b[i];
    __shared__ float red[4];
    #pragma unroll
    for (int off = 32; off > 0; off >>= 1) s += __shfl_down(s, off, 64);
    if ((t & 63) == 0) red[t >> 6] = s;
    __syncthreads();
    if (t == 0) out[0] = (red[0] + red[1] + red[2] + red[3]) * (1.f / B);
}

extern "C" void kernel_launch(void* const* d_in, const int* in_sizes, int n_in,
                              void* d_out, int out_size, void* d_ws, size_t ws_size,
                              hipStream_t stream) {
    const int* x_batch = (const int*)d_in[0];
    const int* ctxw    = (const int*)d_in[1];
    const float* eps   = (const float*)d_in[2];
    const float* inf_emb = (const float*)d_in[3];
    const float* W_aff = (const float*)d_in[4];
    const float* b_aff = (const float*)d_in[5];
    const float* W_mu  = (const float*)d_in[6];
    const float* b_mu  = (const float*)d_in[7];
    const float* W_sig = (const float*)d_in[8];
    const float* b_sig = (const float*)d_in[9];
    const float* gen_sig = (const float*)d_in[10];
    const float* W_gen = (const float*)d_in[11];
    const float* b_gen = (const float*)d_in[12];
    float* out = (float*)d_out;

    char* ws = (char*)d_ws;
    float* z      = (float*)ws;                       ws += (size_t)B * D * 4;   // 1 MB
    float* kl     = (float*)ws;                       ws += (size_t)B * 4;
    float* part_s = (float*)ws;                       ws += (size_t)B * NSTREAM * 4; // 1 MB
    float* loss_b = (float*)ws;                       ws += (size_t)B * 4;
    short* z_bf   = (short*)ws;                       ws += (size_t)B * D * 2;   // 0.5 MB
    short* w_bf   = (short*)ws;                       ws += (size_t)NVPAD * D * 2; // 12.9 MB

    hipLaunchKernelGGL(k_convert_w, dim3((NVPAD * D / 4 + 255) / 256), dim3(256), 0, stream,
                       W_gen, w_bf);
    hipLaunchKernelGGL(k_infer, dim3(B), dim3(128), 0, stream,
                       x_batch, ctxw, eps, inf_emb, W_aff, b_aff, W_mu, b_mu,
                       W_sig, b_sig, gen_sig, z, z_bf, kl);
    hipLaunchKernelGGL(k_lse_mfma, dim3(B / MROWS, NSTREAM / 4), dim3(256), 0, stream,
                       z_bf, w_bf, b_gen, part_s);
    hipLaunchKernelGGL(k_final_row, dim3(B), dim3(64), 0, stream,
                       z, W_gen, b_gen, ctxw, part_s, kl, loss_b);
    hipLaunchKernelGGL(k_reduce, dim3(1), dim3(256), 0, stream, loss_b, out);
}

// Round 3
// 232.853 us; speedup vs baseline: 5.0677x; 1.1865x over previous
//
#include <hip/hip_runtime.h>
#include <float.h>
#include <math.h>

#define NV 50257
#define D 128
#define B 2048
#define C 10

// ---- MFMA LSE kernel geometry ----
#define NVPAD 50272                 // 3142 * 16
#define NTILES (NVPAD / 16)         // 3142 col-tiles of 16
#define NSTREAM 128                 // 32 chunks * 4 waves = independent vocab streams
#define MROWS 64                    // batch rows per block (4 row-tiles of 16)

#define NG4 (NVPAD * D / 4)         // float4 count of padded W_gen

typedef __attribute__((ext_vector_type(8))) short short8;
typedef __attribute__((ext_vector_type(4))) float float4v;

__device__ __forceinline__ float softplus_f(float x) {
    return fmaxf(x, 0.f) + log1pf(expf(-fabsf(x)));
}

__device__ __forceinline__ short f2bf(float f) {
    unsigned u = __float_as_uint(f);
    unsigned r = (u + 0x7FFFu + ((u >> 16) & 1u)) >> 16;   // RNE
    return (short)r;
}

// ---------------- Kernel W: fp32 -> bf16 of W_gen (padded), W_aff, W_mu, W_sig ----------------
__global__ __launch_bounds__(256) void k_convert(
    const float* __restrict__ wg, const float* __restrict__ waff,
    const float* __restrict__ wmu, const float* __restrict__ wsig,
    short* __restrict__ wg_o, short* __restrict__ waff_o,
    short* __restrict__ wmu_o, short* __restrict__ wsig_o)
{
    const int i4 = blockIdx.x * 256 + threadIdx.x;      // float4 index
    if (i4 < NG4) {
        const int e0 = i4 * 4;
        short4 o;
        if (e0 < NV * D) {
            const float4 g = ((const float4*)wg)[i4];
            o.x = f2bf(g.x); o.y = f2bf(g.y); o.z = f2bf(g.z); o.w = f2bf(g.w);
        } else {
            o.x = o.y = o.z = o.w = 0;
        }
        ((short4*)wg_o)[i4] = o;
    } else {
        const int j = i4 - NG4;
        const float4* src; short4* dst; int jj;
        if (j < 8192)       { src = (const float4*)waff; dst = (short4*)waff_o; jj = j; }
        else if (j < 12288) { src = (const float4*)wmu;  dst = (short4*)wmu_o;  jj = j - 8192; }
        else                { src = (const float4*)wsig; dst = (short4*)wsig_o; jj = j - 12288; }
        const float4 g = src[jj];
        short4 o;
        o.x = f2bf(g.x); o.y = f2bf(g.y); o.z = f2bf(g.z); o.w = f2bf(g.w);
        dst[jj] = o;
    }
}

// ---------------- Kernel A: MFMA inference net ----------------
// One wave per 16 batch rows. grid B/16 = 128, block 64.
// A-layout: lane holds row m=lane&15, k-chunk quad*8 (+ks*32).
// C-layout: col=lane&15, row=quad*4+reg.
__global__ __launch_bounds__(64) void k_infer_mfma(
    const int* __restrict__ x_batch, const int* __restrict__ ctxw,
    const float* __restrict__ eps, const float* __restrict__ inf_emb,
    const short* __restrict__ waff_bf, const float* __restrict__ b_aff,
    const short* __restrict__ wmu_bf, const float* __restrict__ b_mu,
    const short* __restrict__ wsig_bf, const float* __restrict__ b_sig,
    const float* __restrict__ gen_sig_emb,
    float* __restrict__ z_out, short* __restrict__ zb_out,
    float* __restrict__ kl_out)
{
    const int b0 = blockIdx.x * 16;
    const int lane = threadIdx.x;       // 0..63
    const int col16 = lane & 15;
    const int quad = lane >> 4;

    __shared__ float hs[16][132];       // padded: +4 floats -> 2-way-max bank aliasing

    // ---- indices for A-side rows (row = col16) ----
    const int brow = b0 + col16;
    const int cidx = x_batch[brow];
    int cwi[C];
    #pragma unroll
    for (int c = 0; c < C; ++c) cwi[c] = ctxw[brow * C + c];

    // ---- center A-frags (gather + cvt) ----
    short8 ce[4];
    #pragma unroll
    for (int ks = 0; ks < 4; ++ks) {
        const float* p = inf_emb + (size_t)cidx * D + ks * 32 + quad * 8;
        const float4 g0 = *(const float4*)p;
        const float4 g1 = *(const float4*)(p + 4);
        short8 v;
        v[0] = f2bf(g0.x); v[1] = f2bf(g0.y); v[2] = f2bf(g0.z); v[3] = f2bf(g0.w);
        v[4] = f2bf(g1.x); v[5] = f2bf(g1.y); v[6] = f2bf(g1.z); v[7] = f2bf(g1.w);
        ce[ks] = v;
    }

    // ---- U = center @ W1^T  (W1 = W_aff[:, 0:128]) ----
    float4v U[8];
    #pragma unroll
    for (int dt = 0; dt < 8; ++dt) {
        float4v acc = {0.f, 0.f, 0.f, 0.f};
        #pragma unroll
        for (int ks = 0; ks < 4; ++ks) {
            const short8 bw = *(const short8*)(waff_bf + (dt * 16 + col16) * 256 + ks * 32 + quad * 8);
            acc = __builtin_amdgcn_mfma_f32_16x16x32_bf16(ce[ks], bw, acc, 0, 0, 0);
        }
        U[dt] = acc;
    }

    float ba[8];
    #pragma unroll
    for (int dt = 0; dt < 8; ++dt) ba[dt] = b_aff[dt * 16 + col16];

    // ---- V per context + relu + sum (all in C-layout registers) ----
    float4v H[8];
    #pragma unroll
    for (int dt = 0; dt < 8; ++dt) H[dt] = (float4v){0.f, 0.f, 0.f, 0.f};

    for (int c = 0; c < C; ++c) {
        short8 cx[4];
        #pragma unroll
        for (int ks = 0; ks < 4; ++ks) {
            const float* p = inf_emb + (size_t)cwi[c] * D + ks * 32 + quad * 8;
            const float4 g0 = *(const float4*)p;
            const float4 g1 = *(const float4*)(p + 4);
            short8 v;
            v[0] = f2bf(g0.x); v[1] = f2bf(g0.y); v[2] = f2bf(g0.z); v[3] = f2bf(g0.w);
            v[4] = f2bf(g1.x); v[5] = f2bf(g1.y); v[6] = f2bf(g1.z); v[7] = f2bf(g1.w);
            cx[ks] = v;
        }
        #pragma unroll
        for (int dt = 0; dt < 8; ++dt) {
            float4v a = {0.f, 0.f, 0.f, 0.f};
            #pragma unroll
            for (int ks = 0; ks < 4; ++ks) {
                const short8 bw = *(const short8*)(waff_bf + (dt * 16 + col16) * 256 + 128 + ks * 32 + quad * 8);
                a = __builtin_amdgcn_mfma_f32_16x16x32_bf16(cx[ks], bw, a, 0, 0, 0);
            }
            #pragma unroll
            for (int r = 0; r < 4; ++r)
                H[dt][r] += fmaxf(U[dt][r] + a[r] + ba[dt], 0.f);
        }
    }

    // ---- C-layout -> LDS -> A-layout for GEMM2 ----
    #pragma unroll
    for (int dt = 0; dt < 8; ++dt)
        #pragma unroll
        for (int r = 0; r < 4; ++r)
            hs[quad * 4 + r][dt * 16 + col16] = H[dt][r];
    __syncthreads();

    short8 ha[4];
    #pragma unroll
    for (int ks = 0; ks < 4; ++ks) {
        const float4 f0 = *(const float4*)&hs[col16][ks * 32 + quad * 8];
        const float4 f1 = *(const float4*)&hs[col16][ks * 32 + quad * 8 + 4];
        short8 v;
        v[0] = f2bf(f0.x); v[1] = f2bf(f0.y); v[2] = f2bf(f0.z); v[3] = f2bf(f0.w);
        v[4] = f2bf(f1.x); v[5] = f2bf(f1.y); v[6] = f2bf(f1.z); v[7] = f2bf(f1.w);
        ha[ks] = v;
    }

    // ---- GEMM2: mu / sig ----
    float4v MU[8], SG[8];
    #pragma unroll
    for (int nt = 0; nt < 8; ++nt) {
        float4v mu = {0.f, 0.f, 0.f, 0.f};
        float4v sg = {0.f, 0.f, 0.f, 0.f};
        #pragma unroll
        for (int ks = 0; ks < 4; ++ks) {
            const short8 bm = *(const short8*)(wmu_bf + (nt * 16 + col16) * 128 + ks * 32 + quad * 8);
            const short8 bs = *(const short8*)(wsig_bf + (nt * 16 + col16) * 128 + ks * 32 + quad * 8);
            mu = __builtin_amdgcn_mfma_f32_16x16x32_bf16(ha[ks], bm, mu, 0, 0, 0);
            sg = __builtin_amdgcn_mfma_f32_16x16x32_bf16(ha[ks], bs, sg, 0, 0, 0);
        }
        MU[nt] = mu; SG[nt] = sg;
    }

    // ---- pointwise epilogue: softplus, z, zb, KL ----
    int xb2[4];
    #pragma unroll
    for (int r = 0; r < 4; ++r) xb2[r] = x_batch[b0 + quad * 4 + r];

    float klp[4] = {0.f, 0.f, 0.f, 0.f};
    #pragma unroll
    for (int nt = 0; nt < 8; ++nt) {
        const int d = nt * 16 + col16;
        const float bmu = b_mu[d];
        const float bsg = b_sig[d];
        #pragma unroll
        for (int r = 0; r < 4; ++r) {
            const int b = b0 + quad * 4 + r;
            const float mu = MU[nt][r] + bmu;
            const float sg = SG[nt][r] + bsg;
            const float isig = softplus_f(sg);
            const float e = eps[b * D + d];
            const float zz = fmaf(e, isig, mu);
            z_out[b * D + d] = zz;
            zb_out[b * D + d] = f2bf(zz);
            const float gs = softplus_f(gen_sig_emb[(size_t)xb2[r] * D + d]);
            const float diff = mu - gs;
            klp[r] += logf(gs / isig) + (isig * isig + diff * diff) / (2.f * gs * gs) - 0.5f;
        }
    }
    #pragma unroll
    for (int off = 1; off < 16; off <<= 1)
        #pragma unroll
        for (int r = 0; r < 4; ++r)
            klp[r] += __shfl_xor(klp[r], off, 64);
    if (col16 == 0) {
        #pragma unroll
        for (int r = 0; r < 4; ++r)
            kl_out[b0 + quad * 4 + r] = klp[r];
    }
}

// ---------------- Kernel B: MFMA sum-exp over vocab (fixed shift 0, no LDS, no barriers) ----
__global__ __launch_bounds__(256) void k_lse_mfma(
    const short* __restrict__ zb, const short* __restrict__ wb,
    const float* __restrict__ b_gen, float* __restrict__ part_s)
{
    const int rowbase = blockIdx.x * MROWS;
    const int t = threadIdx.x;
    const int wv = t >> 6;
    const int lane = t & 63;
    const int col16 = lane & 15;
    const int quad = lane >> 4;
    const int sid = blockIdx.y * 4 + wv;      // 0..127

    short8 afrag[4][4];
    #pragma unroll
    for (int rt = 0; rt < 4; ++rt)
        #pragma unroll
        for (int ks = 0; ks < 4; ++ks)
            afrag[rt][ks] = *(const short8*)(zb + (rowbase + rt * 16 + col16) * D
                                                + ks * 32 + quad * 8);

    float sums[4][4];
    #pragma unroll
    for (int rt = 0; rt < 4; ++rt)
        #pragma unroll
        for (int r = 0; r < 4; ++r) sums[rt][r] = 0.f;

    for (int tile = sid; tile < NTILES; tile += NSTREAM) {
        const int n0 = tile * 16;
        const int col = n0 + col16;
        const short* wp = wb + (size_t)col * D + quad * 8;
        short8 bfrag[4];
        #pragma unroll
        for (int ks = 0; ks < 4; ++ks)
            bfrag[ks] = *(const short8*)(wp + ks * 32);
        const float bgl = b_gen[col < NV ? col : NV - 1];
        const float bg = (col < NV) ? bgl : -INFINITY;

        #pragma unroll
        for (int rt = 0; rt < 4; ++rt) {
            float4v c = {0.f, 0.f, 0.f, 0.f};
            #pragma unroll
            for (int ks = 0; ks < 4; ++ks)
                c = __builtin_amdgcn_mfma_f32_16x16x32_bf16(afrag[rt][ks], bfrag[ks], c, 0, 0, 0);
            #pragma unroll
            for (int r = 0; r < 4; ++r)
                sums[rt][r] += __expf(c[r] + bg);
        }
    }

    #pragma unroll
    for (int off = 1; off < 16; off <<= 1)
        #pragma unroll
        for (int rt = 0; rt < 4; ++rt)
            #pragma unroll
            for (int r = 0; r < 4; ++r)
                sums[rt][r] += __shfl_xor(sums[rt][r], off, 64);

    if (col16 == 0) {
        #pragma unroll
        for (int rt = 0; rt < 4; ++rt)
            #pragma unroll
            for (int r = 0; r < 4; ++r) {
                const int row = rowbase + rt * 16 + quad * 4 + r;
                part_s[row * NSTREAM + sid] = sums[rt][r];
            }
    }
}

// ---------------- Kernel C: per-row finalize ----------------
__global__ __launch_bounds__(64) void k_final_row(
    const float* __restrict__ z, const float* __restrict__ W_gen,
    const float* __restrict__ b_gen, const int* __restrict__ ctxw,
    const float* __restrict__ part_s, const float* __restrict__ kl,
    float* __restrict__ loss_b)
{
    const int b = blockIdx.x;
    const int lane = threadIdx.x;    // 0..63

    float s = part_s[b * NSTREAM + lane] + part_s[b * NSTREAM + 64 + lane];
    #pragma unroll
    for (int off = 32; off > 0; off >>= 1) s += __shfl_xor(s, off, 64);
    const float lse = logf(s);       // fixed shift 0: logits are O(1)

    const float z0 = z[b * D + lane * 2];
    const float z1 = z[b * D + lane * 2 + 1];
    float recon = 0.f;
    for (int c = 0; c < C; ++c) {
        const int idx = ctxw[b * C + c];
        float p = z0 * W_gen[idx * D + lane * 2] + z1 * W_gen[idx * D + lane * 2 + 1];
        #pragma unroll
        for (int off = 32; off > 0; off >>= 1) p += __shfl_xor(p, off, 64);
        recon += p + b_gen[idx] - lse;
    }
    if (lane == 0) loss_b[b] = kl[b] - recon;
}

// ---------------- Kernel D: deterministic mean ----------------
__global__ __launch_bounds__(256) void k_reduce(
    const float* __restrict__ loss_b, float* __restrict__ out)
{
    const int t = threadIdx.x;
    float s = 0.f;
    for (int i = t; i < B; i += 256) s += loss_b[i];
    __shared__ float red[4];
    #pragma unroll
    for (int off = 32; off > 0; off >>= 1) s += __shfl_down(s, off, 64);
    if ((t & 63) == 0) red[t >> 6] = s;
    __syncthreads();
    if (t == 0) out[0] = (red[0] + red[1] + red[2] + red[3]) * (1.f / B);
}

extern "C" void kernel_launch(void* const* d_in, const int* in_sizes, int n_in,
                              void* d_out, int out_size, void* d_ws, size_t ws_size,
                              hipStream_t stream) {
    const int* x_batch = (const int*)d_in[0];
    const int* ctxw    = (const int*)d_in[1];
    const float* eps   = (const float*)d_in[2];
    const float* inf_emb = (const float*)d_in[3];
    const float* W_aff = (const float*)d_in[4];
    const float* b_aff = (const float*)d_in[5];
    const float* W_mu  = (const float*)d_in[6];
    const float* b_mu  = (const float*)d_in[7];
    const float* W_sig = (const float*)d_in[8];
    const float* b_sig = (const float*)d_in[9];
    const float* gen_sig = (const float*)d_in[10];
    const float* W_gen = (const float*)d_in[11];
    const float* b_gen = (const float*)d_in[12];
    float* out = (float*)d_out;

    char* ws = (char*)d_ws;
    float* z      = (float*)ws;   ws += (size_t)B * D * 4;
    float* kl     = (float*)ws;   ws += (size_t)B * 4;
    float* part_s = (float*)ws;   ws += (size_t)B * NSTREAM * 4;
    float* loss_b = (float*)ws;   ws += (size_t)B * 4;
    short* z_bf   = (short*)ws;   ws += (size_t)B * D * 2;
    short* w_bf   = (short*)ws;   ws += (size_t)NVPAD * D * 2;
    short* waff_bf = (short*)ws;  ws += (size_t)128 * 256 * 2;
    short* wmu_bf  = (short*)ws;  ws += (size_t)128 * 128 * 2;
    short* wsig_bf = (short*)ws;  ws += (size_t)128 * 128 * 2;

    hipLaunchKernelGGL(k_convert, dim3((NG4 + 16384) / 256), dim3(256), 0, stream,
                       W_gen, W_aff, W_mu, W_sig, w_bf, waff_bf, wmu_bf, wsig_bf);
    hipLaunchKernelGGL(k_infer_mfma, dim3(B / 16), dim3(64), 0, stream,
                       x_batch, ctxw, eps, inf_emb, waff_bf, b_aff, wmu_bf, b_mu,
                       wsig_bf, b_sig, gen_sig, z, z_bf, kl);
    hipLaunchKernelGGL(k_lse_mfma, dim3(B / MROWS, NSTREAM / 4), dim3(256), 0, stream,
                       z_bf, w_bf, b_gen, part_s);
    hipLaunchKernelGGL(k_final_row, dim3(B), dim3(64), 0, stream,
                       z, W_gen, b_gen, ctxw, part_s, kl, loss_b);
    hipLaunchKernelGGL(k_reduce, dim3(1), dim3(256), 0, stream, loss_b, out);
}

// Round 4
// 232.114 us; speedup vs baseline: 5.0839x; 1.0032x over previous
//
#include <hip/hip_runtime.h>
#include <float.h>
#include <math.h>

#define NV 50257
#define D 128
#define B 2048
#define C 10

#define NVPAD 50272                 // 3142 * 16
#define NTILES (NVPAD / 16)         // 3142 col-tiles of 16
#define NSTREAM 128                 // vocab streams (k_final depends on this)
#define NG4 (NVPAD * D / 4)         // float4 count of padded W_gen
#define LOG2E 1.44269504088896f

typedef __attribute__((ext_vector_type(8))) short short8;
typedef __attribute__((ext_vector_type(4))) float float4v;

__device__ __forceinline__ float softplus_f(float x) {
    return fmaxf(x, 0.f) + log1pf(expf(-fabsf(x)));
}

__device__ __forceinline__ short f2bf(float f) {
    unsigned u = __float_as_uint(f);
    unsigned r = (u + 0x7FFFu + ((u >> 16) & 1u)) >> 16;   // RNE
    return (short)r;
}

// ---------------- Kernel W: bf16 converts + bg2 table + out zeroing ----------------
__global__ __launch_bounds__(256) void k_convert(
    const float* __restrict__ wg, const float* __restrict__ waff,
    const float* __restrict__ wmu, const float* __restrict__ wsig,
    const float* __restrict__ b_gen,
    short* __restrict__ wg_o, short* __restrict__ waff_o,
    short* __restrict__ wmu_o, short* __restrict__ wsig_o,
    float* __restrict__ bg2, float* __restrict__ out)
{
    const int i4 = blockIdx.x * 256 + threadIdx.x;      // float4 index
    if (i4 == 0) out[0] = 0.f;
    if (i4 < NG4) {
        const int e0 = i4 * 4;
        short4 o;
        if (e0 < NV * D) {
            const float4 g = ((const float4*)wg)[i4];
            o.x = f2bf(g.x); o.y = f2bf(g.y); o.z = f2bf(g.z); o.w = f2bf(g.w);
        } else {
            o.x = o.y = o.z = o.w = 0;
        }
        ((short4*)wg_o)[i4] = o;
        return;
    }
    const int j = i4 - NG4;
    if (j < 16384) {
        const float4* src; short4* dst; int jj;
        if (j < 8192)       { src = (const float4*)waff; dst = (short4*)waff_o; jj = j; }
        else if (j < 12288) { src = (const float4*)wmu;  dst = (short4*)wmu_o;  jj = j - 8192; }
        else                { src = (const float4*)wsig; dst = (short4*)wsig_o; jj = j - 12288; }
        const float4 g = src[jj];
        short4 o;
        o.x = f2bf(g.x); o.y = f2bf(g.y); o.z = f2bf(g.z); o.w = f2bf(g.w);
        dst[jj] = o;
    } else {
        const int jj = j - 16384;                       // bg2 float4 index
        if (jj < NVPAD / 4) {
            const int e0 = jj * 4;
            float4 o;
            o.x = (e0 + 0 < NV) ? b_gen[e0 + 0] * LOG2E : -INFINITY;
            o.y = (e0 + 1 < NV) ? b_gen[e0 + 1] * LOG2E : -INFINITY;
            o.z = (e0 + 2 < NV) ? b_gen[e0 + 2] * LOG2E : -INFINITY;
            o.w = (e0 + 3 < NV) ? b_gen[e0 + 3] * LOG2E : -INFINITY;
            ((float4*)bg2)[jj] = o;
        }
    }
}

// ---------------- Kernel A: MFMA inference net, context-parallel over 4 waves ----------
// grid B/16 = 128 blocks x 256 threads. Wave w: contexts c = w, w+4, w+8; then
// GEMM2 + epilogue for nt = 2w, 2w+1. A-layout: row=lane&15, k=quad*8(+ks*32).
// C-layout: col=lane&15, row=quad*4+reg.
__global__ __launch_bounds__(256) void k_infer_mfma(
    const int* __restrict__ x_batch, const int* __restrict__ ctxw,
    const float* __restrict__ eps, const float* __restrict__ inf_emb,
    const short* __restrict__ waff_bf, const float* __restrict__ b_aff,
    const short* __restrict__ wmu_bf, const float* __restrict__ b_mu,
    const short* __restrict__ wsig_bf, const float* __restrict__ b_sig,
    const float* __restrict__ gen_sig_emb,
    float* __restrict__ z_out, short* __restrict__ zb_out,
    float* __restrict__ kl_out)
{
    const int b0 = blockIdx.x * 16;
    const int t = threadIdx.x;
    const int wv = t >> 6;
    const int lane = t & 63;
    const int col16 = lane & 15;
    const int quad = lane >> 4;

    __shared__ float hsp[4][16][132];   // per-wave partial H (C-layout scatter)
    __shared__ float kl_s[4][16];

    const int brow = b0 + col16;
    const int cidx = x_batch[brow];

    // center A-frags (all waves, redundant)
    short8 ce[4];
    #pragma unroll
    for (int ks = 0; ks < 4; ++ks) {
        const float* p = inf_emb + (size_t)cidx * D + ks * 32 + quad * 8;
        const float4 g0 = *(const float4*)p;
        const float4 g1 = *(const float4*)(p + 4);
        short8 v;
        v[0] = f2bf(g0.x); v[1] = f2bf(g0.y); v[2] = f2bf(g0.z); v[3] = f2bf(g0.w);
        v[4] = f2bf(g1.x); v[5] = f2bf(g1.y); v[6] = f2bf(g1.z); v[7] = f2bf(g1.w);
        ce[ks] = v;
    }

    // U = center @ W1^T (redundant per wave)
    float4v U[8];
    #pragma unroll
    for (int dt = 0; dt < 8; ++dt) {
        float4v acc = {0.f, 0.f, 0.f, 0.f};
        #pragma unroll
        for (int ks = 0; ks < 4; ++ks) {
            const short8 bw = *(const short8*)(waff_bf + (dt * 16 + col16) * 256 + ks * 32 + quad * 8);
            acc = __builtin_amdgcn_mfma_f32_16x16x32_bf16(ce[ks], bw, acc, 0, 0, 0);
        }
        U[dt] = acc;
    }
    float ba[8];
    #pragma unroll
    for (int dt = 0; dt < 8; ++dt) ba[dt] = b_aff[dt * 16 + col16];

    // this wave's contexts
    float4v H[8];
    #pragma unroll
    for (int dt = 0; dt < 8; ++dt) H[dt] = (float4v){0.f, 0.f, 0.f, 0.f};

    for (int c = wv; c < C; c += 4) {
        const int widx = ctxw[brow * C + c];
        short8 cx[4];
        #pragma unroll
        for (int ks = 0; ks < 4; ++ks) {
            const float* p = inf_emb + (size_t)widx * D + ks * 32 + quad * 8;
            const float4 g0 = *(const float4*)p;
            const float4 g1 = *(const float4*)(p + 4);
            short8 v;
            v[0] = f2bf(g0.x); v[1] = f2bf(g0.y); v[2] = f2bf(g0.z); v[3] = f2bf(g0.w);
            v[4] = f2bf(g1.x); v[5] = f2bf(g1.y); v[6] = f2bf(g1.z); v[7] = f2bf(g1.w);
            cx[ks] = v;
        }
        #pragma unroll
        for (int dt = 0; dt < 8; ++dt) {
            float4v a = {0.f, 0.f, 0.f, 0.f};
            #pragma unroll
            for (int ks = 0; ks < 4; ++ks) {
                const short8 bw = *(const short8*)(waff_bf + (dt * 16 + col16) * 256 + 128 + ks * 32 + quad * 8);
                a = __builtin_amdgcn_mfma_f32_16x16x32_bf16(cx[ks], bw, a, 0, 0, 0);
            }
            #pragma unroll
            for (int r = 0; r < 4; ++r)
                H[dt][r] += fmaxf(U[dt][r] + a[r] + ba[dt], 0.f);
        }
    }

    // partial H -> LDS (C-layout)
    #pragma unroll
    for (int dt = 0; dt < 8; ++dt)
        #pragma unroll
        for (int r = 0; r < 4; ++r)
            hsp[wv][quad * 4 + r][dt * 16 + col16] = H[dt][r];
    __syncthreads();

    // ha = sum of 4 wave partials, A-layout
    short8 ha[4];
    #pragma unroll
    for (int ks = 0; ks < 4; ++ks) {
        const int off = ks * 32 + quad * 8;
        float4 s0 = {0.f, 0.f, 0.f, 0.f}, s1 = {0.f, 0.f, 0.f, 0.f};
        #pragma unroll
        for (int w = 0; w < 4; ++w) {
            const float4 a0 = *(const float4*)&hsp[w][col16][off];
            const float4 a1 = *(const float4*)&hsp[w][col16][off + 4];
            s0.x += a0.x; s0.y += a0.y; s0.z += a0.z; s0.w += a0.w;
            s1.x += a1.x; s1.y += a1.y; s1.z += a1.z; s1.w += a1.w;
        }
        short8 v;
        v[0] = f2bf(s0.x); v[1] = f2bf(s0.y); v[2] = f2bf(s0.z); v[3] = f2bf(s0.w);
        v[4] = f2bf(s1.x); v[5] = f2bf(s1.y); v[6] = f2bf(s1.z); v[7] = f2bf(s1.w);
        ha[ks] = v;
    }

    // GEMM2 + epilogue: wave w handles nt = 2w, 2w+1
    int xb2[4];
    #pragma unroll
    for (int r = 0; r < 4; ++r) xb2[r] = x_batch[b0 + quad * 4 + r];

    float klp[4] = {0.f, 0.f, 0.f, 0.f};
    #pragma unroll
    for (int p = 0; p < 2; ++p) {
        const int nt = wv * 2 + p;
        float4v mu4 = {0.f, 0.f, 0.f, 0.f};
        float4v sg4 = {0.f, 0.f, 0.f, 0.f};
        #pragma unroll
        for (int ks = 0; ks < 4; ++ks) {
            const short8 bm = *(const short8*)(wmu_bf + (nt * 16 + col16) * 128 + ks * 32 + quad * 8);
            const short8 bs = *(const short8*)(wsig_bf + (nt * 16 + col16) * 128 + ks * 32 + quad * 8);
            mu4 = __builtin_amdgcn_mfma_f32_16x16x32_bf16(ha[ks], bm, mu4, 0, 0, 0);
            sg4 = __builtin_amdgcn_mfma_f32_16x16x32_bf16(ha[ks], bs, sg4, 0, 0, 0);
        }
        const int d = nt * 16 + col16;
        const float bmu = b_mu[d];
        const float bsg = b_sig[d];
        #pragma unroll
        for (int r = 0; r < 4; ++r) {
            const int b = b0 + quad * 4 + r;
            const float mu = mu4[r] + bmu;
            const float sg = sg4[r] + bsg;
            const float isig = softplus_f(sg);
            const float e = eps[b * D + d];
            const float zz = fmaf(e, isig, mu);
            z_out[b * D + d] = zz;
            zb_out[b * D + d] = f2bf(zz);
            const float gs = softplus_f(gen_sig_emb[(size_t)xb2[r] * D + d]);
            const float diff = mu - gs;
            klp[r] += logf(gs / isig) + (isig * isig + diff * diff) / (2.f * gs * gs) - 0.5f;
        }
    }
    #pragma unroll
    for (int off = 1; off < 16; off <<= 1)
        #pragma unroll
        for (int r = 0; r < 4; ++r)
            klp[r] += __shfl_xor(klp[r], off, 64);
    if (col16 == 0) {
        #pragma unroll
        for (int r = 0; r < 4; ++r)
            kl_s[wv][quad * 4 + r] = klp[r];
    }
    __syncthreads();
    if (t < 16) kl_out[b0 + t] = kl_s[0][t] + kl_s[1][t] + kl_s[2][t] + kl_s[3][t];
}

// ---------------- Kernel B: MFMA sum-exp; 4 waves share one stream over 256 rows ------
// grid 1024 (1D, XCD-swizzled), block 256. bid%8 selects XCD-local stream group.
__global__ __launch_bounds__(256) void k_lse_mfma(
    const short* __restrict__ zb, const short* __restrict__ wb,
    const float* __restrict__ bg2t, float* __restrict__ part_s)
{
    const int bid = blockIdx.x;
    const int r7 = bid & 127;
    const int sid = ((r7 & 7) << 4) | (r7 >> 3);   // stream 0..127; same XCD -> 16 streams
    const int x = bid >> 7;                         // row block 0..7 (256 rows each)
    const int t = threadIdx.x;
    const int wv = t >> 6;
    const int lane = t & 63;
    const int col16 = lane & 15;
    const int quad = lane >> 4;
    const int rowbase = x * 256 + wv * 64;

    short8 afrag[4][4];
    #pragma unroll
    for (int rt = 0; rt < 4; ++rt)
        #pragma unroll
        for (int ks = 0; ks < 4; ++ks)
            afrag[rt][ks] = *(const short8*)(zb + (rowbase + rt * 16 + col16) * D
                                                + ks * 32 + quad * 8);

    float sums[4][4];
    #pragma unroll
    for (int rt = 0; rt < 4; ++rt)
        #pragma unroll
        for (int r = 0; r < 4; ++r) sums[rt][r] = 0.f;

    for (int tile = sid; tile < NTILES; tile += NSTREAM) {
        const int col = tile * 16 + col16;
        const short* wp = wb + (size_t)col * D + quad * 8;
        short8 bfrag[4];
        #pragma unroll
        for (int ks = 0; ks < 4; ++ks)
            bfrag[ks] = *(const short8*)(wp + ks * 32);
        const float bg2 = bg2t[col];               // padded: -inf on pad cols

        #pragma unroll
        for (int rt = 0; rt < 4; ++rt) {
            float4v c = {0.f, 0.f, 0.f, 0.f};
            #pragma unroll
            for (int ks = 0; ks < 4; ++ks)
                c = __builtin_amdgcn_mfma_f32_16x16x32_bf16(afrag[rt][ks], bfrag[ks], c, 0, 0, 0);
            #pragma unroll
            for (int r = 0; r < 4; ++r)
                sums[rt][r] += __builtin_amdgcn_exp2f(fmaf(c[r], LOG2E, bg2));
        }
    }

    #pragma unroll
    for (int off = 1; off < 16; off <<= 1)
        #pragma unroll
        for (int rt = 0; rt < 4; ++rt)
            #pragma unroll
            for (int r = 0; r < 4; ++r)
                sums[rt][r] += __shfl_xor(sums[rt][r], off, 64);

    if (col16 == 0) {
        #pragma unroll
        for (int rt = 0; rt < 4; ++rt)
            #pragma unroll
            for (int r = 0; r < 4; ++r) {
                const int row = rowbase + rt * 16 + quad * 4 + r;
                part_s[row * NSTREAM + sid] = sums[rt][r];
            }
    }
}

// ---------------- Kernel C: per-row finalize + fused mean (atomic) ----------------
__global__ __launch_bounds__(64) void k_final_row(
    const float* __restrict__ z, const short* __restrict__ wb,
    const float* __restrict__ b_gen, const int* __restrict__ ctxw,
    const float* __restrict__ part_s, const float* __restrict__ kl,
    float* __restrict__ out)
{
    const int b = blockIdx.x;
    const int lane = threadIdx.x;    // 0..63

    float s = part_s[b * NSTREAM + lane] + part_s[b * NSTREAM + 64 + lane];
    #pragma unroll
    for (int off = 32; off > 0; off >>= 1) s += __shfl_xor(s, off, 64);
    const float lse = logf(s);       // fixed shift 0: logits are O(1)

    const float z0 = z[b * D + lane * 2];
    const float z1 = z[b * D + lane * 2 + 1];
    float recon = 0.f;
    for (int c = 0; c < C; ++c) {
        const int idx = ctxw[b * C + c];
        const unsigned u = ((const unsigned*)(wb + (size_t)idx * D))[lane];
        const float w0 = __uint_as_float(u << 16);
        const float w1 = __uint_as_float(u & 0xFFFF0000u);
        float p = z0 * w0 + z1 * w1;
        #pragma unroll
        for (int off = 32; off > 0; off >>= 1) p += __shfl_xor(p, off, 64);
        recon += p + b_gen[idx] - lse;
    }
    if (lane == 0) atomicAdd(out, (kl[b] - recon) * (1.f / B));
}

extern "C" void kernel_launch(void* const* d_in, const int* in_sizes, int n_in,
                              void* d_out, int out_size, void* d_ws, size_t ws_size,
                              hipStream_t stream) {
    const int* x_batch = (const int*)d_in[0];
    const int* ctxw    = (const int*)d_in[1];
    const float* eps   = (const float*)d_in[2];
    const float* inf_emb = (const float*)d_in[3];
    const float* W_aff = (const float*)d_in[4];
    const float* b_aff = (const float*)d_in[5];
    const float* W_mu  = (const float*)d_in[6];
    const float* b_mu  = (const float*)d_in[7];
    const float* W_sig = (const float*)d_in[8];
    const float* b_sig = (const float*)d_in[9];
    const float* gen_sig = (const float*)d_in[10];
    const float* W_gen = (const float*)d_in[11];
    const float* b_gen = (const float*)d_in[12];
    float* out = (float*)d_out;

    char* ws = (char*)d_ws;
    float* z      = (float*)ws;   ws += (size_t)B * D * 4;
    float* part_s = (float*)ws;   ws += (size_t)B * NSTREAM * 4;
    float* kl     = (float*)ws;   ws += (size_t)B * 4;
    float* bg2    = (float*)ws;   ws += (size_t)NVPAD * 4;
    short* z_bf   = (short*)ws;   ws += (size_t)B * D * 2;
    short* w_bf   = (short*)ws;   ws += (size_t)NVPAD * D * 2;
    short* waff_bf = (short*)ws;  ws += (size_t)128 * 256 * 2;
    short* wmu_bf  = (short*)ws;  ws += (size_t)128 * 128 * 2;
    short* wsig_bf = (short*)ws;  ws += (size_t)128 * 128 * 2;

    const int conv_items = NG4 + 16384 + NVPAD / 4;
    hipLaunchKernelGGL(k_convert, dim3((conv_items + 255) / 256), dim3(256), 0, stream,
                       W_gen, W_aff, W_mu, W_sig, b_gen,
                       w_bf, waff_bf, wmu_bf, wsig_bf, bg2, out);
    hipLaunchKernelGGL(k_infer_mfma, dim3(B / 16), dim3(256), 0, stream,
                       x_batch, ctxw, eps, inf_emb, waff_bf, b_aff, wmu_bf, b_mu,
                       wsig_bf, b_sig, gen_sig, z, z_bf, kl);
    hipLaunchKernelGGL(k_lse_mfma, dim3(B / 256 * NSTREAM), dim3(256), 0, stream,
                       z_bf, w_bf, bg2, part_s);
    hipLaunchKernelGGL(k_final_row, dim3(B), dim3(64), 0, stream,
                       z, w_bf, b_gen, ctxw, part_s, kl, out);
}